// Round 4
// baseline (1448.098 us; speedup 1.0000x reference)
//
#include <hip/hip_runtime.h>

#define NROWS 8192
#define NCOLS 8192
#define DIM   512
#define BM 64
#define BN 64
#define BK 32
#define NSPLIT 4
#define SLICE (NCOLS / NSPLIT)   // 2048
#define NCT (SLICE / BN)         // 32

// ---------------------------------------------------------------------------
// Kernel 1: row norms of both descriptor sets (f64 accumulate). One wave/row.
// ---------------------------------------------------------------------------
__global__ __launch_bounds__(256) void dm_norms(const float* __restrict__ d1,
                                                const float* __restrict__ d2,
                                                double* __restrict__ n1,
                                                double* __restrict__ n2) {
    const int wave = threadIdx.x >> 6;
    const int lane = threadIdx.x & 63;
    const int r = blockIdx.x * 4 + wave;   // 0 .. 16383
    const float* src = (r < NROWS) ? (d1 + (size_t)r * DIM)
                                   : (d2 + (size_t)(r - NROWS) * DIM);
    float4 a = *(const float4*)(src + lane * 4);
    float4 b = *(const float4*)(src + 256 + lane * 4);
    double s = (double)a.x * a.x + (double)a.y * a.y
             + (double)a.z * a.z + (double)a.w * a.w
             + (double)b.x * b.x + (double)b.y * b.y
             + (double)b.z * b.z + (double)b.w * b.w;
#pragma unroll
    for (int m = 32; m >= 1; m >>= 1) s += __shfl_xor(s, m);
    if (lane == 0) {
        if (r < NROWS) n1[r] = s;
        else           n2[r - NROWS] = s;
    }
}

// ---------------------------------------------------------------------------
// Kernel 2: fused distance-GEMM + per-row top-2 (on s = ||b||^2 - 2 a.b).
// Block: 64 rows x 2048-column slice. 256 threads, 4x4 register tile.
// LDS: k-major [BK][64] tiles, XOR-swizzled (col ^ ((k>>2)<<2)) so both the
// transpose-stores and the float4 reads are conflict-free (<=2-way).
// Numerics: f32 FMA within each BK=32 k-tile, folded into f64 accumulators
// (16 f64 adds / 1024 FLOPs ~ 4% cost) so our dot error ~1e-5 — argmin
// flips vs the reference become reference-noise-limited.
// ---------------------------------------------------------------------------
__global__ __launch_bounds__(256) void dm_match(const float* __restrict__ d1,
                                                const float* __restrict__ d2,
                                                const double* __restrict__ n2,
                                                double* __restrict__ pv0,
                                                double* __restrict__ pv1,
                                                int* __restrict__ pi0) {
    __shared__ float As[BK][BM];
    __shared__ float Bs[BK][BN];

    const int rb   = blockIdx.x / NSPLIT;
    const int sp   = blockIdx.x % NSPLIT;
    const int row0 = rb * BM;
    const int col0 = sp * SLICE;

    const int tid = threadIdx.x;
    const int tx  = tid & 15;         // column group 0..15
    const int ty  = tid >> 4;         // row group 0..15
    const int sc  = tid >> 3;         // staging row-in-tile 0..31
    const int sk  = (tid & 7) << 2;   // staging k offset 0,4,..,28

    double v0[4], v1[4];
    int    i0[4];
#pragma unroll
    for (int r = 0; r < 4; ++r) { v0[r] = 1.0e300; v1[r] = 1.0e300; i0[r] = 0; }

    for (int ct = 0; ct < NCT; ++ct) {
        const int c0 = col0 + ct * BN;
        double acc64[4][4];
#pragma unroll
        for (int r = 0; r < 4; ++r)
#pragma unroll
            for (int c = 0; c < 4; ++c) acc64[r][c] = 0.0;

        for (int kk = 0; kk < DIM; kk += BK) {
            // issue global loads before the barrier so they overlap the wait
            float4 a0 = *(const float4*)(d1 + (size_t)(row0 + sc)      * DIM + kk + sk);
            float4 a1 = *(const float4*)(d1 + (size_t)(row0 + sc + 32) * DIM + kk + sk);
            float4 b0 = *(const float4*)(d2 + (size_t)(c0  + sc)      * DIM + kk + sk);
            float4 b1 = *(const float4*)(d2 + (size_t)(c0  + sc + 32) * DIM + kk + sk);
            __syncthreads();           // previous stage fully consumed
            {
                const int wc0 = sc ^ sk;          // swizzle: ((k>>2)<<2) == sk here
                const int wc1 = (sc + 32) ^ sk;
                As[sk + 0][wc0] = a0.x; As[sk + 1][wc0] = a0.y;
                As[sk + 2][wc0] = a0.z; As[sk + 3][wc0] = a0.w;
                As[sk + 0][wc1] = a1.x; As[sk + 1][wc1] = a1.y;
                As[sk + 2][wc1] = a1.z; As[sk + 3][wc1] = a1.w;
                Bs[sk + 0][wc0] = b0.x; Bs[sk + 1][wc0] = b0.y;
                Bs[sk + 2][wc0] = b0.z; Bs[sk + 3][wc0] = b0.w;
                Bs[sk + 0][wc1] = b1.x; Bs[sk + 1][wc1] = b1.y;
                Bs[sk + 2][wc1] = b1.z; Bs[sk + 3][wc1] = b1.w;
            }
            __syncthreads();

            float acc[4][4];
#pragma unroll
            for (int r = 0; r < 4; ++r)
#pragma unroll
                for (int c = 0; c < 4; ++c) acc[r][c] = 0.f;

#pragma unroll
            for (int k = 0; k < BK; ++k) {
                const int rsw = (k >> 2) << 2;
                float4 a = *(const float4*)&As[k][(ty * 4) ^ rsw];
                float4 b = *(const float4*)&Bs[k][(tx * 4) ^ rsw];
                acc[0][0] = fmaf(a.x, b.x, acc[0][0]);
                acc[0][1] = fmaf(a.x, b.y, acc[0][1]);
                acc[0][2] = fmaf(a.x, b.z, acc[0][2]);
                acc[0][3] = fmaf(a.x, b.w, acc[0][3]);
                acc[1][0] = fmaf(a.y, b.x, acc[1][0]);
                acc[1][1] = fmaf(a.y, b.y, acc[1][1]);
                acc[1][2] = fmaf(a.y, b.z, acc[1][2]);
                acc[1][3] = fmaf(a.y, b.w, acc[1][3]);
                acc[2][0] = fmaf(a.z, b.x, acc[2][0]);
                acc[2][1] = fmaf(a.z, b.y, acc[2][1]);
                acc[2][2] = fmaf(a.z, b.z, acc[2][2]);
                acc[2][3] = fmaf(a.z, b.w, acc[2][3]);
                acc[3][0] = fmaf(a.w, b.x, acc[3][0]);
                acc[3][1] = fmaf(a.w, b.y, acc[3][1]);
                acc[3][2] = fmaf(a.w, b.z, acc[3][2]);
                acc[3][3] = fmaf(a.w, b.w, acc[3][3]);
            }
            // fold the f32 tile-partial into the f64 accumulator
#pragma unroll
            for (int r = 0; r < 4; ++r)
#pragma unroll
                for (int c = 0; c < 4; ++c) acc64[r][c] += (double)acc[r][c];
        }

        // top-2 update on s = n2[j] - 2*dot  (monotone in distance per row).
        // Columns ascend per thread, preserving top_k's lowest-index-first
        // tie behavior.
        const int cbase = c0 + tx * 4;
        double nna[4];
#pragma unroll
        for (int c = 0; c < 4; ++c) nna[c] = n2[cbase + c];
#pragma unroll
        for (int r = 0; r < 4; ++r) {
#pragma unroll
            for (int c = 0; c < 4; ++c) {
                const double s = nna[c] - 2.0 * acc64[r][c];
                const int j = cbase + c;
                if (s < v0[r]) { v1[r] = v0[r]; v0[r] = s; i0[r] = j; }
                else if (s < v1[r]) { v1[r] = s; }
            }
        }
    }

    // reduce across the 16 threads (tx) sharing each row; explicit index
    // tie-break keeps lowest-index-wins.
#pragma unroll
    for (int r = 0; r < 4; ++r) {
        double a0 = v0[r], a1 = v1[r];
        int    ai = i0[r];
#pragma unroll
        for (int m = 1; m <= 8; m <<= 1) {
            double b0 = __shfl_xor(a0, m);
            double b1 = __shfl_xor(a1, m);
            int    bi = __shfl_xor(ai, m);
            bool take = (b0 < a0) || (b0 == a0 && bi < ai);
            if (take) { a1 = fmin(a0, b1); a0 = b0; ai = bi; }
            else      { a1 = fmin(a1, b0); }
        }
        if (tx == 0) {
            const int row = row0 + ty * 4 + r;
            pv0[sp * NROWS + row] = a0;
            pv1[sp * NROWS + row] = a1;
            pi0[sp * NROWS + row] = ai;
        }
    }
}

// ---------------------------------------------------------------------------
// Kernel 3: merge the NSPLIT partials, sqrt + ratio test, write outputs.
// Output layout (all as float): [0,8192) dists(=ratio where masked),
// [8192,24576) idx pairs, [24576,32768) mask.
// ---------------------------------------------------------------------------
__global__ __launch_bounds__(256) void dm_finalize(const double* __restrict__ n1,
                                                   const double* __restrict__ pv0,
                                                   const double* __restrict__ pv1,
                                                   const int* __restrict__ pi0,
                                                   float* __restrict__ out) {
    const int i = blockIdx.x * blockDim.x + threadIdx.x;
    if (i >= NROWS) return;
    double a0 = pv0[i], a1 = pv1[i];
    int    ai = pi0[i];
#pragma unroll
    for (int h = 1; h < NSPLIT; ++h) {
        const double b0 = pv0[h * NROWS + i];
        const double b1 = pv1[h * NROWS + i];
        const int    bi = pi0[h * NROWS + i];
        bool take = (b0 < a0) || (b0 == a0 && bi < ai);
        if (take) { a1 = fmin(a0, b1); a0 = b0; ai = bi; }
        else      { a1 = fmin(a1, b0); }
    }
    const double nn = n1[i];
    const double d0  = sqrt(fmax(nn + a0, 0.0));
    const double d1v = sqrt(fmax(nn + a1, 0.0));
    const float ratio = (float)(d0 / d1v);
    const bool mask = (ratio <= 0.8f);
    out[i] = mask ? ratio : 0.f;
    out[NROWS + 2 * i]     = (float)i;
    out[NROWS + 2 * i + 1] = (float)ai;
    out[3 * NROWS + i] = mask ? 1.f : 0.f;
}

extern "C" void kernel_launch(void* const* d_in, const int* in_sizes, int n_in,
                              void* d_out, int out_size, void* d_ws, size_t ws_size,
                              hipStream_t stream) {
    const float* d1 = (const float*)d_in[0];
    const float* d2 = (const float*)d_in[1];
    float* out = (float*)d_out;

    double* n1  = (double*)d_ws;                 // 8192 f64
    double* n2  = n1 + NROWS;                    // 8192 f64
    double* pv0 = n2 + NROWS;                    // NSPLIT*8192 f64
    double* pv1 = pv0 + NSPLIT * NROWS;          // NSPLIT*8192 f64
    int*    pi0 = (int*)(pv1 + NSPLIT * NROWS);  // NSPLIT*8192 i32
    // total ws: 768 KiB

    dm_norms<<<(2 * NROWS) / 4, 256, 0, stream>>>(d1, d2, n1, n2);
    dm_match<<<(NROWS / BM) * NSPLIT, 256, 0, stream>>>(d1, d2, n2, pv0, pv1, pi0);
    dm_finalize<<<NROWS / 256, 256, 0, stream>>>(n1, pv0, pv1, pi0, out);
}